// Round 8
// baseline (480.086 us; speedup 1.0000x reference)
//
#include <hip/hip_runtime.h>

typedef __attribute__((ext_vector_type(8))) short short8;
typedef __attribute__((ext_vector_type(4))) float f32x4;

#define NROW 8192
#define D_SZ 512

// workspace byte offsets.
// [0, 8388608) = hb (bf16 H) during feature phase; label path reuses it after.
// NOTE (r7 bug): everything written BEFORE/DURING the feature phase must live
// OUTSIDE [0, 8388608). psum_part/fpart were inside -> corrupted hb -> NaN.
#define HB_OFF     0u         // bf16 [8192][512] = 8388608 B   (feature phase)
#define SPARTL_OFF 0u         // f32 [16][256][256] = 4194304 B (label phase, aliases hb)
#define SGRAM_OFF  4194304u   // f32 [256][256] = 262144 B      (label phase, aliases hb)
#define POS_OFF    8388608u   // f32 [8192] = 32768 B
#define DSUM_OFF   8421376u   // f64 [8192] = 65536 B  (unnormalized exp-sums)
#define PSUMP_OFF  8486912u   // f32 [32][128] = 16384 B (prep writes; outside hb!)
#define FPART_OFF  8503296u   // f32 [32] (combine output; outside hb + label regions)

// async global->LDS, 16B per lane; LDS dest must be linear (uniform base + lane*16)
#define GLOAD_LDS(gp, lp)                                     \
  __builtin_amdgcn_global_load_lds(                           \
      (const __attribute__((address_space(1))) void*)(gp),    \
      (__attribute__((address_space(3))) void*)(lp), 16, 0, 0)

__device__ __forceinline__ unsigned short f32_to_bf16(float f) {
  unsigned int u = __float_as_uint(f);
  u = (u + 0x7FFFu + ((u >> 16) & 1u)) >> 16;
  return (unsigned short)u;
}

// e^x as f64 for x in ~[-700, 600]: 2^n * 2^frac, frac via v_exp_f32.
__device__ __forceinline__ double exp_pos(float x) {
  if (x < -700.f) return 0.0;
  float t = x * 1.44269504f;
  float n = floorf(t);
  double m = (double)exp2f(t - n);
  int ni = (int)n;
  double sc = __hiloint2double((1023 + ni) << 20, 0);
  return m * sc;
}

// ---- fused prep: h->bf16 convert + pos dots + label column sums + dsum zero ----
// b < 2048: convert rows 2b,2b+1 of h1/h2 -> hb rows r, 4096+r; pos[r]=2*h1_r.h2_r
// 2048 <= b < 2080: colsum of q1/q2 -> psum_part (32 blocks)
// b == 2080: zero dsum[8192] (f64)
__global__ void prep_kernel(const float* __restrict__ h1, const float* __restrict__ h2,
                            const float* __restrict__ q1, const float* __restrict__ q2,
                            unsigned short* __restrict__ hb, float* __restrict__ pos,
                            double* __restrict__ dsum, float* __restrict__ psum_part) {
  const int b = blockIdx.x, t = threadIdx.x;
  if (b < 2048) {
    __shared__ float dr_[4];
    const int r0 = b * 2;
    const int r = r0 + (t >> 7);
    const int off4 = (t & 127) * 4;
    float4 a = *reinterpret_cast<const float4*>(h1 + (size_t)r * D_SZ + off4);
    float4 c = *reinterpret_cast<const float4*>(h2 + (size_t)r * D_SZ + off4);
    ushort4 oa, oc;
    oa.x = f32_to_bf16(a.x); oa.y = f32_to_bf16(a.y);
    oa.z = f32_to_bf16(a.z); oa.w = f32_to_bf16(a.w);
    oc.x = f32_to_bf16(c.x); oc.y = f32_to_bf16(c.y);
    oc.z = f32_to_bf16(c.z); oc.w = f32_to_bf16(c.w);
    *reinterpret_cast<ushort4*>(hb + (size_t)r * D_SZ + off4) = oa;
    *reinterpret_cast<ushort4*>(hb + (size_t)(4096 + r) * D_SZ + off4) = oc;
    float d = a.x * c.x + a.y * c.y + a.z * c.z + a.w * c.w;
#pragma unroll
    for (int off = 1; off < 64; off <<= 1) d += __shfl_xor(d, off);
    if ((t & 63) == 0) dr_[t >> 6] = d;
    __syncthreads();
    if (t == 0) {
      float v = 2.f * (dr_[0] + dr_[1]);
      pos[r0] = v; pos[r0 + 4096] = v;
    } else if (t == 128) {
      float v = 2.f * (dr_[2] + dr_[3]);
      pos[r0 + 1] = v; pos[r0 + 1 + 4096] = v;
    }
  } else if (b < 2080) {
    __shared__ float sd[256];
    int idx = b - 2048;  // 0..31: q = idx>>4, row-block = idx&15
    const float* q = (idx < 16) ? q1 : q2;
    int col = t & 127, rh = t >> 7;
    int rbase = (idx & 15) * 256 + rh;
    float acc = 0.f;
    for (int i = 0; i < 128; ++i) acc += q[(rbase + 2 * i) * 128 + col];
    sd[t] = acc;
    __syncthreads();
    if (t < 128) psum_part[idx * 128 + col] = sd[t] + sd[t + 128];
  } else {
#pragma unroll
    for (int k = 0; k < 32; ++k) dsum[t + 256 * k] = 0.0;
  }
}

// ---------------- feature NT-Xent via symmetric tiles ----------------
// 528 blocks = upper-triangle 256x256 tiles (ti<=tj). Inner loop = r5's verified
// 2-phase BK=64 dbuf structure (involution swizzle, 0 bank conflicts, swapped MFMA).
// Epilogue: unnormalized exp-sums in f64, atomically added per row (row-side) and,
// for off-diagonal tiles, per column (transpose-side) -> halves GEMM+LDS work.
__global__ __launch_bounds__(512, 2) void feature_kernel(
    const short* __restrict__ hb, double* __restrict__ dsum) {
  __shared__ short lds_s[2][2][16384];  // [buf][A=0/B=1][256 rows x 64 k] bf16 swizzled
  const int tid = threadIdx.x;
  const int w = tid >> 6;
  const int lane = tid & 63;
  const int lo16 = lane & 15;
  const int grp = lane >> 4;
  const int lo7 = lo16 & 7;
  const int wr = w >> 2;            // 0..1 row-half
  const int wc = w & 3;             // 0..3 col-quarter

  // linear block id -> upper-triangle tile (ti, tj)
  int ti = 0, rem = blockIdx.x;
#pragma unroll 1
  while (rem >= 32 - ti) { rem -= 32 - ti; ++ti; }
  const int tj = ti + rem;
  const int R0 = ti * 256, C0 = tj * 256;
  const bool diag = (ti == tj);

  // staging: thread stages chunk (tid&7) of rows {i*64 + (tid>>3)}, pre-swizzled source
  const int srow = tid >> 3;
  const int csrc = (tid & 7) ^ (srow & 7);
  const short* baseA = hb + (size_t)(R0 + srow) * D_SZ + csrc * 8;
  const short* baseB = hb + (size_t)(C0 + srow) * D_SZ + csrc * 8;

#define STAGE_STEP(bk_, buf_) do {                             \
    const short* sa_ = baseA + (bk_) * 64;                     \
    const short* sb_ = baseB + (bk_) * 64;                     \
    short* da_ = &lds_s[buf_][0][tid * 8];                     \
    short* db_ = &lds_s[buf_][1][tid * 8];                     \
    GLOAD_LDS(sa_, da_);                  GLOAD_LDS(sb_, db_);                  \
    GLOAD_LDS(sa_ + 32768, da_ + 4096);   GLOAD_LDS(sb_ + 32768, db_ + 4096);   \
    GLOAD_LDS(sa_ + 65536, da_ + 8192);   GLOAD_LDS(sb_ + 65536, db_ + 8192);   \
    GLOAD_LDS(sa_ + 98304, da_ + 12288);  GLOAD_LDS(sb_ + 98304, db_ + 12288);  \
  } while (0)

  f32x4 acc[4][8];
#pragma unroll
  for (int cf = 0; cf < 4; ++cf)
#pragma unroll
    for (int rf = 0; rf < 8; ++rf) acc[cf][rf] = (f32x4){0, 0, 0, 0};

  const int rowbaseA = (wr * 128 + lo16) * 64;
  const int colbaseB = (wc * 64 + lo16) * 64;

  STAGE_STEP(0, 0);
  __syncthreads();

#pragma unroll 1
  for (int bk = 0; bk < 8; ++bk) {
    const int buf = bk & 1;
    if (bk < 7) STAGE_STEP(bk + 1, buf ^ 1);
    const short* pA = &lds_s[buf][0][0];
    const short* pB = &lds_s[buf][1][0];
#pragma unroll
    for (int ksub = 0; ksub < 2; ++ksub) {
      const int chsw = ((ksub * 4 + grp) ^ lo7) * 8;
      short8 cf_[4], rf_[8];
#pragma unroll
      for (int cf = 0; cf < 4; ++cf)
        cf_[cf] = *reinterpret_cast<const short8*>(&pB[colbaseB + cf * 1024 + chsw]);
#pragma unroll
      for (int rf = 0; rf < 8; ++rf)
        rf_[rf] = *reinterpret_cast<const short8*>(&pA[rowbaseA + rf * 1024 + chsw]);
#pragma unroll
      for (int cf = 0; cf < 4; ++cf)
#pragma unroll
        for (int rf = 0; rf < 8; ++rf)
          acc[cf][rf] = __builtin_amdgcn_mfma_f32_16x16x32_bf16(cf_[cf], rf_[rf],
                                                                acc[cf][rf], 0, 0, 0);
    }
    __syncthreads();
  }

  // ---- epilogue: f64 exp-sum contributions (swapped layout: lane row = +lo16,
  //      cols = C0 + wc*64 + cf*16 + grp*4 + j) ----
  // row-side (always)
#pragma unroll
  for (int rf = 0; rf < 8; ++rf) {
    const int row = R0 + wr * 128 + rf * 16 + lo16;
    double rsum = 0.0;
#pragma unroll
    for (int cf = 0; cf < 4; ++cf)
#pragma unroll
      for (int j = 0; j < 4; ++j) {
        if (diag && (C0 + wc * 64 + cf * 16 + grp * 4 + j) == row) continue;
        rsum += exp_pos(acc[cf][rf][j] * 2.f);
      }
    rsum += __shfl_xor(rsum, 16);
    rsum += __shfl_xor(rsum, 32);
    if (grp == 0) atomicAdd(&dsum[row], rsum);
  }
  // transpose-side (off-diagonal tiles only), two cf-half passes to cap registers
  if (!diag) {
#pragma unroll 1
    for (int half = 0; half < 2; ++half) {
      double colp[8] = {0, 0, 0, 0, 0, 0, 0, 0};
#pragma unroll
      for (int rf = 0; rf < 8; ++rf)
#pragma unroll
        for (int k = 0; k < 8; ++k)
          colp[k] += exp_pos(acc[half * 2 + (k >> 2)][rf][k & 3] * 2.f);
#pragma unroll
      for (int off = 1; off < 16; off <<= 1)
#pragma unroll
        for (int k = 0; k < 8; ++k) colp[k] += __shfl_xor(colp[k], off);
      if (lo16 < 8) {
        double myv = 0.0;
#pragma unroll
        for (int k = 0; k < 8; ++k) myv = (lo16 == k) ? colp[k] : myv;  // static idx
        const int c = C0 + wc * 64 + (half * 2 + (lo16 >> 2)) * 16 + grp * 4 + (lo16 & 3);
        atomicAdd(&dsum[c], myv);
      }
    }
  }
#undef STAGE_STEP
}

__global__ void combine_feature_kernel(const double* __restrict__ dsum,
                                       const float* __restrict__ pos,
                                       const float* __restrict__ conf,
                                       float* __restrict__ fpart) {
  __shared__ float red[256];
  int r = blockIdx.x * 256 + threadIdx.x;
  double d = dsum[r];
  int e2 = ((__double2hiint(d) >> 20) & 0x7ff) - 1023;
  double mant = d * __hiloint2double((1023 - e2) << 20, 0);  // in [1,2)
  float lse = logf((float)mant) + (float)e2 * 0.69314718f;
  float loss = (lse - pos[r]) * conf[r & 4095];
  red[threadIdx.x] = loss;
  __syncthreads();
  for (int s = 128; s > 0; s >>= 1) {
    if (threadIdx.x < s) red[threadIdx.x] += red[threadIdx.x + s];
    __syncthreads();
  }
  if (threadIdx.x == 0) fpart[blockIdx.x] = red[0];
}

// ---------------- label path: S = X^T X, X = [q1 | q2] (4096 x 256), f32 ----------------
__global__ __launch_bounds__(256) void label_gemm_kernel(const float* __restrict__ q1,
                                                         const float* __restrict__ q2,
                                                         float* __restrict__ Spart) {
  __shared__ float As[32 * 64];
  __shared__ float Bs[32 * 64];
  const int t = threadIdx.x;
  const int kz = blockIdx.x >> 4;
  const int bi = (blockIdx.x >> 2) & 3;
  const int bj = blockIdx.x & 3;
  const int tx = t & 15, ty = t >> 4;
  float a[4][4];
#pragma unroll
  for (int dr = 0; dr < 4; ++dr)
#pragma unroll
    for (int dc = 0; dc < 4; ++dc) a[dr][dc] = 0.f;

  for (int ch = 0; ch < 8; ++ch) {
    const int kbase = kz * 256 + ch * 32;
    __syncthreads();
#pragma unroll
    for (int i = 0; i < 8; ++i) {
      int e = i * 256 + t;
      int kr = e >> 6, j = e & 63;
      int ca = bi * 64 + j;
      int cb = bj * 64 + j;
      As[kr * 64 + j] = (ca < 128) ? q1[(kbase + kr) * 128 + ca]
                                   : q2[(kbase + kr) * 128 + ca - 128];
      Bs[kr * 64 + j] = (cb < 128) ? q1[(kbase + kr) * 128 + cb]
                                   : q2[(kbase + kr) * 128 + cb - 128];
    }
    __syncthreads();
#pragma unroll 8
    for (int k = 0; k < 32; ++k) {
      float4 Av = *reinterpret_cast<const float4*>(&As[k * 64 + ty * 4]);
      float4 Bv = *reinterpret_cast<const float4*>(&Bs[k * 64 + tx * 4]);
      a[0][0] += Av.x * Bv.x; a[0][1] += Av.x * Bv.y; a[0][2] += Av.x * Bv.z; a[0][3] += Av.x * Bv.w;
      a[1][0] += Av.y * Bv.x; a[1][1] += Av.y * Bv.y; a[1][2] += Av.y * Bv.z; a[1][3] += Av.y * Bv.w;
      a[2][0] += Av.z * Bv.x; a[2][1] += Av.z * Bv.y; a[2][2] += Av.z * Bv.z; a[2][3] += Av.z * Bv.w;
      a[3][0] += Av.w * Bv.x; a[3][1] += Av.w * Bv.y; a[3][2] += Av.w * Bv.z; a[3][3] += Av.w * Bv.w;
    }
  }
  float* outp = Spart + (size_t)kz * 65536;
#pragma unroll
  for (int dr = 0; dr < 4; ++dr) {
    int r = bi * 64 + ty * 4 + dr;
    int c = bj * 64 + tx * 4;
    float4 o = {a[dr][0], a[dr][1], a[dr][2], a[dr][3]};
    *reinterpret_cast<float4*>(&outp[r * 256 + c]) = o;
  }
}

// combine Spart -> S (256 blocks)
__global__ void label_combine_kernel(const float* __restrict__ Spart,
                                     float* __restrict__ S) {
  int e = blockIdx.x * 256 + threadIdx.x;
  float acc = 0.f;
#pragma unroll
  for (int kz = 0; kz < 16; ++kz) acc += Spart[(size_t)kz * 65536 + e];
  S[e] = acc;
}

__global__ __launch_bounds__(256) void label_final_kernel(
    const float* __restrict__ S, const float* __restrict__ psum_part,
    const float* __restrict__ fpart, float* __restrict__ out) {
  __shared__ float nrm[256], red[256], redl[256];
  __shared__ float entropy_sh, feat_sh;
  const int t = threadIdx.x;
  nrm[t] = sqrtf(fmaxf(S[t * 257], 0.f));
  const float* pp = psum_part + (t >> 7) * 2048 + (t & 127);
  float v = 0.f;
#pragma unroll
  for (int i = 0; i < 16; ++i) v += pp[i * 128];
  red[t] = v;
  redl[t] = v * logf(fmaxf(v, 1e-30f));
  __syncthreads();
  for (int s = 64; s > 0; s >>= 1) {
    if ((t & 127) < s) { red[t] += red[t + s]; redl[t] += redl[t + s]; }
    __syncthreads();
  }
  if (t == 0) {
    float tot1 = red[0], tot2 = red[128];
    float ne1 = logf(128.f) + (redl[0] / tot1 - logf(tot1));
    float ne2 = logf(128.f) + (redl[128] / tot2 - logf(tot2));
    entropy_sh = ne1 + ne2;
  }
  __syncthreads();
  red[t] = (t < 32) ? fpart[t] : 0.f;
  __syncthreads();
  for (int s = 128; s > 0; s >>= 1) {
    if (t < s) red[t] += red[t + s];
    __syncthreads();
  }
  if (t == 0) feat_sh = red[0];
  __syncthreads();

  const float nr = nrm[t];
  const float* Srow = S + t * 256;
  const int partner = (t + 128) & 255;
  float m = -INFINITY;
  for (int c = 0; c < 256; ++c) {
    if (c == t) continue;
    float sv = Srow[c] / fmaxf(nr * nrm[c], 1e-8f);
    m = fmaxf(m, sv);
  }
  float ssum = 0.f, posv = 0.f;
  for (int c = 0; c < 256; ++c) {
    float sv = Srow[c] / fmaxf(nr * nrm[c], 1e-8f);
    if (c == partner) posv = sv;
    if (c != t) ssum += __expf(sv - m);
  }
  float loss_r = (logf(ssum) + m) - posv;
  __syncthreads();
  red[t] = loss_r;
  __syncthreads();
  for (int s = 128; s > 0; s >>= 1) {
    if (t < s) red[t] += red[t + s];
    __syncthreads();
  }
  if (t == 0)
    out[0] = 0.5f * (feat_sh / 8192.f) + 0.5f * (red[0] / 256.f + entropy_sh);
}

extern "C" void kernel_launch(void* const* d_in, const int* in_sizes, int n_in,
                              void* d_out, int out_size, void* d_ws, size_t ws_size,
                              hipStream_t stream) {
  const float* h1 = (const float*)d_in[0];
  const float* h2 = (const float*)d_in[1];
  const float* q1 = (const float*)d_in[2];
  const float* q2 = (const float*)d_in[3];
  const float* conf = (const float*)d_in[4];
  float* out = (float*)d_out;
  char* ws = (char*)d_ws;

  unsigned short* hb = (unsigned short*)(ws + HB_OFF);
  float* pos    = (float*)(ws + POS_OFF);
  double* dsum  = (double*)(ws + DSUM_OFF);
  float* SpartL = (float*)(ws + SPARTL_OFF);
  float* Sgram  = (float*)(ws + SGRAM_OFF);
  float* psump  = (float*)(ws + PSUMP_OFF);
  float* fpart  = (float*)(ws + FPART_OFF);

  prep_kernel<<<2081, 256, 0, stream>>>(h1, h2, q1, q2, hb, pos, dsum, psump);
  feature_kernel<<<528, 512, 0, stream>>>((const short*)hb, dsum);
  combine_feature_kernel<<<32, 256, 0, stream>>>(dsum, pos, conf, fpart);
  // hb region is dead from here on; label path reuses it.
  label_gemm_kernel<<<256, 256, 0, stream>>>(q1, q2, SpartL);
  label_combine_kernel<<<256, 256, 0, stream>>>(SpartL, Sgram);
  label_final_kernel<<<1, 256, 0, stream>>>(Sgram, psump, fpart, out);
}

// Round 9
// 245.026 us; speedup vs baseline: 1.9593x; 1.9593x over previous
//
#include <hip/hip_runtime.h>

typedef __attribute__((ext_vector_type(8))) short short8;
typedef __attribute__((ext_vector_type(4))) float f32x4;

#define NROW 8192
#define D_SZ 512

// workspace byte offsets.
// [0, 8388608) = hb (bf16 H) during feature phase; label path reuses it after.
// Everything written BEFORE/DURING the feature phase lives OUTSIDE [0, 8388608).
#define HB_OFF     0u         // bf16 [8192][512] = 8388608 B   (feature phase)
#define SPARTL_OFF 0u         // f32 [16][256][256] = 4194304 B (label phase, aliases hb)
#define SGRAM_OFF  4194304u   // f32 [256][256] = 262144 B      (label phase, aliases hb)
#define POS_OFF    8388608u   // f32 [8192] = 32768 B
#define DSUM_OFF   8421376u   // f64 [8192] = 65536 B  (unnormalized exp-sums)
#define PSUMP_OFF  8486912u   // f32 [32][128] = 16384 B (prep writes; outside hb!)
#define FPART_OFF  8503296u   // f32 [32] (combine output; outside hb + label regions)

// async global->LDS, 16B per lane; LDS dest must be linear (uniform base + lane*16)
#define GLOAD_LDS(gp, lp)                                     \
  __builtin_amdgcn_global_load_lds(                           \
      (const __attribute__((address_space(1))) void*)(gp),    \
      (__attribute__((address_space(3))) void*)(lp), 16, 0, 0)

__device__ __forceinline__ unsigned short f32_to_bf16(float f) {
  unsigned int u = __float_as_uint(f);
  u = (u + 0x7FFFu + ((u >> 16) & 1u)) >> 16;
  return (unsigned short)u;
}

// e^x as f64 for x in ~[-700, 600]: 2^n * 2^frac, frac via v_exp_f32.
__device__ __forceinline__ double exp_pos(float x) {
  if (x < -700.f) return 0.0;
  float t = x * 1.44269504f;
  float n = floorf(t);
  double m = (double)exp2f(t - n);
  int ni = (int)n;
  double sc = __hiloint2double((1023 + ni) << 20, 0);
  return m * sc;
}

// ---- fused prep: h->bf16 convert + pos dots + label column sums + dsum zero ----
__global__ void prep_kernel(const float* __restrict__ h1, const float* __restrict__ h2,
                            const float* __restrict__ q1, const float* __restrict__ q2,
                            unsigned short* __restrict__ hb, float* __restrict__ pos,
                            double* __restrict__ dsum, float* __restrict__ psum_part) {
  const int b = blockIdx.x, t = threadIdx.x;
  if (b < 2048) {
    __shared__ float dr_[4];
    const int r0 = b * 2;
    const int r = r0 + (t >> 7);
    const int off4 = (t & 127) * 4;
    float4 a = *reinterpret_cast<const float4*>(h1 + (size_t)r * D_SZ + off4);
    float4 c = *reinterpret_cast<const float4*>(h2 + (size_t)r * D_SZ + off4);
    ushort4 oa, oc;
    oa.x = f32_to_bf16(a.x); oa.y = f32_to_bf16(a.y);
    oa.z = f32_to_bf16(a.z); oa.w = f32_to_bf16(a.w);
    oc.x = f32_to_bf16(c.x); oc.y = f32_to_bf16(c.y);
    oc.z = f32_to_bf16(c.z); oc.w = f32_to_bf16(c.w);
    *reinterpret_cast<ushort4*>(hb + (size_t)r * D_SZ + off4) = oa;
    *reinterpret_cast<ushort4*>(hb + (size_t)(4096 + r) * D_SZ + off4) = oc;
    float d = a.x * c.x + a.y * c.y + a.z * c.z + a.w * c.w;
#pragma unroll
    for (int off = 1; off < 64; off <<= 1) d += __shfl_xor(d, off);
    if ((t & 63) == 0) dr_[t >> 6] = d;
    __syncthreads();
    if (t == 0) {
      float v = 2.f * (dr_[0] + dr_[1]);
      pos[r0] = v; pos[r0 + 4096] = v;
    } else if (t == 128) {
      float v = 2.f * (dr_[2] + dr_[3]);
      pos[r0 + 1] = v; pos[r0 + 1 + 4096] = v;
    }
  } else if (b < 2080) {
    __shared__ float sd[256];
    int idx = b - 2048;  // 0..31: q = idx>>4, row-block = idx&15
    const float* q = (idx < 16) ? q1 : q2;
    int col = t & 127, rh = t >> 7;
    int rbase = (idx & 15) * 256 + rh;
    float acc = 0.f;
    for (int i = 0; i < 128; ++i) acc += q[(rbase + 2 * i) * 128 + col];
    sd[t] = acc;
    __syncthreads();
    if (t < 128) psum_part[idx * 128 + col] = sd[t] + sd[t + 128];
  } else {
#pragma unroll
    for (int k = 0; k < 32; ++k) dsum[t + 256 * k] = 0.0;
  }
}

// ---------------- feature NT-Xent via symmetric tiles ----------------
// 528 blocks = upper-triangle 256x256 tiles (ti<=tj). Inner loop = verified
// 2-phase BK=64 dbuf structure (involution swizzle, 0 bank conflicts, swapped MFMA).
// Epilogue: STATIC-INDEX-ONLY (r8 lesson / rule #20: runtime index into acc
// demotes the whole array to scratch). One exp_pos per element feeds BOTH the
// row-side sum and the col-side (transpose) sum.
__global__ __launch_bounds__(512, 2) void feature_kernel(
    const short* __restrict__ hb, double* __restrict__ dsum) {
  __shared__ short lds_s[2][2][16384];  // [buf][A=0/B=1][256 rows x 64 k] bf16 swizzled
  const int tid = threadIdx.x;
  const int w = tid >> 6;
  const int lane = tid & 63;
  const int lo16 = lane & 15;
  const int grp = lane >> 4;
  const int lo7 = lo16 & 7;
  const int wr = w >> 2;            // 0..1 row-half
  const int wc = w & 3;             // 0..3 col-quarter

  // linear block id -> upper-triangle tile (ti, tj)
  int ti = 0, rem = blockIdx.x;
#pragma unroll 1
  while (rem >= 32 - ti) { rem -= 32 - ti; ++ti; }
  const int tj = ti + rem;
  const int R0 = ti * 256, C0 = tj * 256;
  const bool diag = (ti == tj);

  // staging: thread stages chunk (tid&7) of rows {i*64 + (tid>>3)}, pre-swizzled source
  const int srow = tid >> 3;
  const int csrc = (tid & 7) ^ (srow & 7);
  const short* baseA = hb + (size_t)(R0 + srow) * D_SZ + csrc * 8;
  const short* baseB = hb + (size_t)(C0 + srow) * D_SZ + csrc * 8;

#define STAGE_STEP(bk_, buf_) do {                             \
    const short* sa_ = baseA + (bk_) * 64;                     \
    const short* sb_ = baseB + (bk_) * 64;                     \
    short* da_ = &lds_s[buf_][0][tid * 8];                     \
    short* db_ = &lds_s[buf_][1][tid * 8];                     \
    GLOAD_LDS(sa_, da_);                  GLOAD_LDS(sb_, db_);                  \
    GLOAD_LDS(sa_ + 32768, da_ + 4096);   GLOAD_LDS(sb_ + 32768, db_ + 4096);   \
    GLOAD_LDS(sa_ + 65536, da_ + 8192);   GLOAD_LDS(sb_ + 65536, db_ + 8192);   \
    GLOAD_LDS(sa_ + 98304, da_ + 12288);  GLOAD_LDS(sb_ + 98304, db_ + 12288);  \
  } while (0)

  f32x4 acc[4][8];
#pragma unroll
  for (int cf = 0; cf < 4; ++cf)
#pragma unroll
    for (int rf = 0; rf < 8; ++rf) acc[cf][rf] = (f32x4){0, 0, 0, 0};

  const int rowbaseA = (wr * 128 + lo16) * 64;
  const int colbaseB = (wc * 64 + lo16) * 64;

  STAGE_STEP(0, 0);
  __syncthreads();

#pragma unroll 1
  for (int bk = 0; bk < 8; ++bk) {
    const int buf = bk & 1;
    if (bk < 7) STAGE_STEP(bk + 1, buf ^ 1);
    const short* pA = &lds_s[buf][0][0];
    const short* pB = &lds_s[buf][1][0];
#pragma unroll
    for (int ksub = 0; ksub < 2; ++ksub) {
      const int chsw = ((ksub * 4 + grp) ^ lo7) * 8;
      short8 cf_[4], rf_[8];
#pragma unroll
      for (int cf = 0; cf < 4; ++cf)
        cf_[cf] = *reinterpret_cast<const short8*>(&pB[colbaseB + cf * 1024 + chsw]);
#pragma unroll
      for (int rf = 0; rf < 8; ++rf)
        rf_[rf] = *reinterpret_cast<const short8*>(&pA[rowbaseA + rf * 1024 + chsw]);
#pragma unroll
      for (int cf = 0; cf < 4; ++cf)
#pragma unroll
        for (int rf = 0; rf < 8; ++rf)
          acc[cf][rf] = __builtin_amdgcn_mfma_f32_16x16x32_bf16(cf_[cf], rf_[rf],
                                                                acc[cf][rf], 0, 0, 0);
    }
    __syncthreads();
  }

  // ---- epilogue: f64 exp-sums, all acc indices compile-time constant ----
  // lane element (cf,rf,j): row = R0+wr*128+rf*16+lo16, col = C0+wc*64+cf*16+grp*4+j
  double rsum[8];
#pragma unroll
  for (int rf = 0; rf < 8; ++rf) rsum[rf] = 0.0;

#pragma unroll
  for (int cf = 0; cf < 4; ++cf) {
    double cs0 = 0.0, cs1 = 0.0, cs2 = 0.0, cs3 = 0.0;
    const int cb = C0 + wc * 64 + cf * 16 + grp * 4;
#pragma unroll
    for (int rf = 0; rf < 8; ++rf) {
      const int row = R0 + wr * 128 + rf * 16 + lo16;
      double e0 = (diag && cb + 0 == row) ? 0.0 : exp_pos(acc[cf][rf][0] * 2.f);
      double e1 = (diag && cb + 1 == row) ? 0.0 : exp_pos(acc[cf][rf][1] * 2.f);
      double e2 = (diag && cb + 2 == row) ? 0.0 : exp_pos(acc[cf][rf][2] * 2.f);
      double e3 = (diag && cb + 3 == row) ? 0.0 : exp_pos(acc[cf][rf][3] * 2.f);
      rsum[rf] += (e0 + e1) + (e2 + e3);
      cs0 += e0; cs1 += e1; cs2 += e2; cs3 += e3;
    }
    if (!diag) {
      // reduce over the 16 lanes of this grp (lane bits 0..3)
#pragma unroll
      for (int off = 1; off < 16; off <<= 1) {
        cs0 += __shfl_xor(cs0, off);
        cs1 += __shfl_xor(cs1, off);
        cs2 += __shfl_xor(cs2, off);
        cs3 += __shfl_xor(cs3, off);
      }
      if (lo16 < 4) {
        double v = (lo16 == 0) ? cs0 : (lo16 == 1) ? cs1 : (lo16 == 2) ? cs2 : cs3;
        atomicAdd(&dsum[cb + lo16], v);
      }
    }
  }
  // row-side: reduce across the 4 grp copies (lane bits 4,5), then atomic
#pragma unroll
  for (int rf = 0; rf < 8; ++rf) {
    double r = rsum[rf];
    r += __shfl_xor(r, 16);
    r += __shfl_xor(r, 32);
    if (grp == 0) atomicAdd(&dsum[R0 + wr * 128 + rf * 16 + lo16], r);
  }
#undef STAGE_STEP
}

__global__ void combine_feature_kernel(const double* __restrict__ dsum,
                                       const float* __restrict__ pos,
                                       const float* __restrict__ conf,
                                       float* __restrict__ fpart) {
  __shared__ float red[256];
  int r = blockIdx.x * 256 + threadIdx.x;
  double d = dsum[r];
  int e2 = ((__double2hiint(d) >> 20) & 0x7ff) - 1023;
  double mant = d * __hiloint2double((1023 - e2) << 20, 0);  // in [1,2)
  float lse = logf((float)mant) + (float)e2 * 0.69314718f;
  float loss = (lse - pos[r]) * conf[r & 4095];
  red[threadIdx.x] = loss;
  __syncthreads();
  for (int s = 128; s > 0; s >>= 1) {
    if (threadIdx.x < s) red[threadIdx.x] += red[threadIdx.x + s];
    __syncthreads();
  }
  if (threadIdx.x == 0) fpart[blockIdx.x] = red[0];
}

// ---------------- label path: S = X^T X, X = [q1 | q2] (4096 x 256), f32 ----------------
__global__ __launch_bounds__(256) void label_gemm_kernel(const float* __restrict__ q1,
                                                         const float* __restrict__ q2,
                                                         float* __restrict__ Spart) {
  __shared__ float As[32 * 64];
  __shared__ float Bs[32 * 64];
  const int t = threadIdx.x;
  const int kz = blockIdx.x >> 4;
  const int bi = (blockIdx.x >> 2) & 3;
  const int bj = blockIdx.x & 3;
  const int tx = t & 15, ty = t >> 4;
  float a[4][4];
#pragma unroll
  for (int dr = 0; dr < 4; ++dr)
#pragma unroll
    for (int dc = 0; dc < 4; ++dc) a[dr][dc] = 0.f;

  for (int ch = 0; ch < 8; ++ch) {
    const int kbase = kz * 256 + ch * 32;
    __syncthreads();
#pragma unroll
    for (int i = 0; i < 8; ++i) {
      int e = i * 256 + t;
      int kr = e >> 6, j = e & 63;
      int ca = bi * 64 + j;
      int cb = bj * 64 + j;
      As[kr * 64 + j] = (ca < 128) ? q1[(kbase + kr) * 128 + ca]
                                   : q2[(kbase + kr) * 128 + ca - 128];
      Bs[kr * 64 + j] = (cb < 128) ? q1[(kbase + kr) * 128 + cb]
                                   : q2[(kbase + kr) * 128 + cb - 128];
    }
    __syncthreads();
#pragma unroll 8
    for (int k = 0; k < 32; ++k) {
      float4 Av = *reinterpret_cast<const float4*>(&As[k * 64 + ty * 4]);
      float4 Bv = *reinterpret_cast<const float4*>(&Bs[k * 64 + tx * 4]);
      a[0][0] += Av.x * Bv.x; a[0][1] += Av.x * Bv.y; a[0][2] += Av.x * Bv.z; a[0][3] += Av.x * Bv.w;
      a[1][0] += Av.y * Bv.x; a[1][1] += Av.y * Bv.y; a[1][2] += Av.y * Bv.z; a[1][3] += Av.y * Bv.w;
      a[2][0] += Av.z * Bv.x; a[2][1] += Av.z * Bv.y; a[2][2] += Av.z * Bv.z; a[2][3] += Av.z * Bv.w;
      a[3][0] += Av.w * Bv.x; a[3][1] += Av.w * Bv.y; a[3][2] += Av.w * Bv.z; a[3][3] += Av.w * Bv.w;
    }
  }
  float* outp = Spart + (size_t)kz * 65536;
#pragma unroll
  for (int dr = 0; dr < 4; ++dr) {
    int r = bi * 64 + ty * 4 + dr;
    int c = bj * 64 + tx * 4;
    float4 o = {a[dr][0], a[dr][1], a[dr][2], a[dr][3]};
    *reinterpret_cast<float4*>(&outp[r * 256 + c]) = o;
  }
}

// combine Spart -> S (256 blocks)
__global__ void label_combine_kernel(const float* __restrict__ Spart,
                                     float* __restrict__ S) {
  int e = blockIdx.x * 256 + threadIdx.x;
  float acc = 0.f;
#pragma unroll
  for (int kz = 0; kz < 16; ++kz) acc += Spart[(size_t)kz * 65536 + e];
  S[e] = acc;
}

__global__ __launch_bounds__(256) void label_final_kernel(
    const float* __restrict__ S, const float* __restrict__ psum_part,
    const float* __restrict__ fpart, float* __restrict__ out) {
  __shared__ float nrm[256], red[256], redl[256];
  __shared__ float entropy_sh, feat_sh;
  const int t = threadIdx.x;
  nrm[t] = sqrtf(fmaxf(S[t * 257], 0.f));
  const float* pp = psum_part + (t >> 7) * 2048 + (t & 127);
  float v = 0.f;
#pragma unroll
  for (int i = 0; i < 16; ++i) v += pp[i * 128];
  red[t] = v;
  redl[t] = v * logf(fmaxf(v, 1e-30f));
  __syncthreads();
  for (int s = 64; s > 0; s >>= 1) {
    if ((t & 127) < s) { red[t] += red[t + s]; redl[t] += redl[t + s]; }
    __syncthreads();
  }
  if (t == 0) {
    float tot1 = red[0], tot2 = red[128];
    float ne1 = logf(128.f) + (redl[0] / tot1 - logf(tot1));
    float ne2 = logf(128.f) + (redl[128] / tot2 - logf(tot2));
    entropy_sh = ne1 + ne2;
  }
  __syncthreads();
  red[t] = (t < 32) ? fpart[t] : 0.f;
  __syncthreads();
  for (int s = 128; s > 0; s >>= 1) {
    if (t < s) red[t] += red[t + s];
    __syncthreads();
  }
  if (t == 0) feat_sh = red[0];
  __syncthreads();

  const float nr = nrm[t];
  const float* Srow = S + t * 256;
  const int partner = (t + 128) & 255;
  float m = -INFINITY;
  for (int c = 0; c < 256; ++c) {
    if (c == t) continue;
    float sv = Srow[c] / fmaxf(nr * nrm[c], 1e-8f);
    m = fmaxf(m, sv);
  }
  float ssum = 0.f, posv = 0.f;
  for (int c = 0; c < 256; ++c) {
    float sv = Srow[c] / fmaxf(nr * nrm[c], 1e-8f);
    if (c == partner) posv = sv;
    if (c != t) ssum += __expf(sv - m);
  }
  float loss_r = (logf(ssum) + m) - posv;
  __syncthreads();
  red[t] = loss_r;
  __syncthreads();
  for (int s = 128; s > 0; s >>= 1) {
    if (t < s) red[t] += red[t + s];
    __syncthreads();
  }
  if (t == 0)
    out[0] = 0.5f * (feat_sh / 8192.f) + 0.5f * (red[0] / 256.f + entropy_sh);
}

extern "C" void kernel_launch(void* const* d_in, const int* in_sizes, int n_in,
                              void* d_out, int out_size, void* d_ws, size_t ws_size,
                              hipStream_t stream) {
  const float* h1 = (const float*)d_in[0];
  const float* h2 = (const float*)d_in[1];
  const float* q1 = (const float*)d_in[2];
  const float* q2 = (const float*)d_in[3];
  const float* conf = (const float*)d_in[4];
  float* out = (float*)d_out;
  char* ws = (char*)d_ws;

  unsigned short* hb = (unsigned short*)(ws + HB_OFF);
  float* pos    = (float*)(ws + POS_OFF);
  double* dsum  = (double*)(ws + DSUM_OFF);
  float* SpartL = (float*)(ws + SPARTL_OFF);
  float* Sgram  = (float*)(ws + SGRAM_OFF);
  float* psump  = (float*)(ws + PSUMP_OFF);
  float* fpart  = (float*)(ws + FPART_OFF);

  prep_kernel<<<2081, 256, 0, stream>>>(h1, h2, q1, q2, hb, pos, dsum, psump);
  feature_kernel<<<528, 512, 0, stream>>>((const short*)hb, dsum);
  combine_feature_kernel<<<32, 256, 0, stream>>>(dsum, pos, conf, fpart);
  // hb region is dead from here on; label path reuses it.
  label_gemm_kernel<<<256, 256, 0, stream>>>(q1, q2, SpartL);
  label_combine_kernel<<<256, 256, 0, stream>>>(SpartL, Sgram);
  label_final_kernel<<<1, 256, 0, stream>>>(Sgram, psump, fpart, out);
}